// Round 1
// baseline (567.896 us; speedup 1.0000x reference)
//
#include <hip/hip_runtime.h>
#include <hip/hip_bf16.h>
#include <stdint.h>

// Varlen causal GQA prefill attention, MI355X (gfx950).
// Shapes fixed by the reference: B=4, S=2048, Hq=16, Hkv=4, D=128, fp32 I/O.
#define NH   16
#define HKVN 4
#define D    128
#define SEQ  2048
#define BATCH 4
#define QTILE 64   // q rows per block (16 per wave, 4 waves)
#define KVC   64   // kv rows per chunk

// (1/sqrt(128)) * log2(e): fold softmax scale + exp2 conversion into Q.
#define SCALE_LOG2E 0.12751741f

typedef __attribute__((ext_vector_type(4))) float  f32x4;
typedef __attribute__((ext_vector_type(8))) short  s16x8;
typedef __attribute__((ext_vector_type(4))) short  s16x4;
typedef __attribute__((ext_vector_type(8))) __bf16 bf16x8;

__device__ __forceinline__ short f2bf(float f) {
  union { float f; uint32_t u; } c; c.f = f;
  uint32_t u = c.u;
  uint32_t r = (u + 0x7FFFu + ((u >> 16) & 1u)) >> 16;  // RNE
  return (short)r;
}

__device__ __forceinline__ f32x4 mfma16(s16x8 a, s16x8 b, f32x4 c) {
  return __builtin_amdgcn_mfma_f32_16x16x32_bf16(
      __builtin_bit_cast(bf16x8, a), __builtin_bit_cast(bf16x8, b), c, 0, 0, 0);
}

__global__ __launch_bounds__(256, 2) void attn_fwd(
    const float* __restrict__ Q, const float* __restrict__ K,
    const float* __restrict__ V, float* __restrict__ O) {
  // LDS: K row-major [64][128] bf16, XOR-swizzled (byte ^= (row&7)<<4) so the
  // stride-256B column reads of B-frags are conflict-free.
  // V subtiled [kv/4][d/16][4][16] bf16 for ds_read_b64_tr_b16.
  // P per-wave [16][72] bf16 (144B row stride -> conflict-free b128 reads).
  __shared__ __align__(16) short Kb[KVC * D];
  __shared__ __align__(16) short Vb[KVC * D];
  __shared__ __align__(16) short Pb[4][16 * 72];

  const int bid = blockIdx.x;
  const int qt  = 31 - (bid & 31);   // heavy q-tiles dispatch first
  const int bh  = bid >> 5;          // 0..63 = b*16 + hq
  const int b   = bh >> 4;
  const int hq  = bh & 15;
  const int hkv = hq >> 2;           // G=4

  const int tid  = threadIdx.x;
  const int wave = tid >> 6;
  const int lane = tid & 63;
  const int lg   = lane >> 4;        // 16-lane group 0..3
  const int lr   = lane & 15;

  const int q0 = qt * QTILE;
  const int qb = q0 + wave * 16;     // this wave's 16 q rows

  // ---- Q fragments (A-frag: row = lr, k = lg*8 + j within each 32-wide kk) --
  const float* qptr = Q + (size_t)(b * SEQ + qb + lr) * (NH * D) + hq * D;
  s16x8 qf[4];
#pragma unroll
  for (int kk = 0; kk < 4; ++kk) {
    f32x4 x0 = *(const f32x4*)(qptr + kk * 32 + lg * 8);
    f32x4 x1 = *(const f32x4*)(qptr + kk * 32 + lg * 8 + 4);
    s16x8 f;
    f[0] = f2bf(x0[0] * SCALE_LOG2E); f[1] = f2bf(x0[1] * SCALE_LOG2E);
    f[2] = f2bf(x0[2] * SCALE_LOG2E); f[3] = f2bf(x0[3] * SCALE_LOG2E);
    f[4] = f2bf(x1[0] * SCALE_LOG2E); f[5] = f2bf(x1[1] * SCALE_LOG2E);
    f[6] = f2bf(x1[2] * SCALE_LOG2E); f[7] = f2bf(x1[3] * SCALE_LOG2E);
    qf[kk] = f;
  }

  f32x4 acc[8];
#pragma unroll
  for (int dt = 0; dt < 8; ++dt) acc[dt] = (f32x4){0.f, 0.f, 0.f, 0.f};
  float m_[4] = {-1e30f, -1e30f, -1e30f, -1e30f};
  float l_[4] = {0.f, 0.f, 0.f, 0.f};

  const float* kbase = K + (size_t)b * SEQ * (HKVN * D) + hkv * D;
  const float* vbase = V + (size_t)b * SEQ * (HKVN * D) + hkv * D;

  const int srow = tid >> 2;  // staging: 4 threads per kv row
  const int ssub = tid & 3;
  const uint32_t vb_base = (uint32_t)(uintptr_t)Vb;  // low 32 bits = LDS offset

  const int nchunks = qt + 1;  // causal: kv in [0, q0+64)
  for (int c = 0; c < nchunks; ++c) {
    const int kvb = c * KVC;
    // ---- stage K,V chunk: fp32 -> bf16, swizzled / subtiled --------------
    {
      const float* krow = kbase + (size_t)(kvb + srow) * (HKVN * D);
      const float* vrow = vbase + (size_t)(kvb + srow) * (HKVN * D);
#pragma unroll
      for (int i = 0; i < 8; ++i) {
        const int col = i * 16 + ssub * 4;
        f32x4 kx = *(const f32x4*)(krow + col);
        f32x4 vx = *(const f32x4*)(vrow + col);
        s16x4 kh, vh;
        kh[0] = f2bf(kx[0]); kh[1] = f2bf(kx[1]);
        kh[2] = f2bf(kx[2]); kh[3] = f2bf(kx[3]);
        vh[0] = f2bf(vx[0]); vh[1] = f2bf(vx[1]);
        vh[2] = f2bf(vx[2]); vh[3] = f2bf(vx[3]);
        *(s16x4*)(&Kb[srow * D + (col ^ ((srow & 7) << 3))]) = kh;
        *(s16x4*)(&Vb[((srow >> 2) * 8 + (col >> 4)) * 64 +
                      (srow & 3) * 16 + (col & 15)]) = vh;
      }
    }
    __syncthreads();

    // ---- S = Q K^T (4 n-tiles of 16 kv, K=128 over 4 MFMAs each) ---------
    f32x4 s[4];
#pragma unroll
    for (int nt = 0; nt < 4; ++nt) s[nt] = (f32x4){0.f, 0.f, 0.f, 0.f};
#pragma unroll
    for (int nt = 0; nt < 4; ++nt) {
      const int kr = nt * 16 + lr;
#pragma unroll
      for (int kk = 0; kk < 4; ++kk) {
        s16x8 bf = *(const s16x8*)(&Kb[kr * D + ((kk * 32 + lg * 8) ^ ((kr & 7) << 3))]);
        s[nt] = mfma16(qf[kk], bf, s[nt]);
      }
    }

    // ---- causal mask + online softmax (rows = lg*4 + r) ------------------
#pragma unroll
    for (int nt = 0; nt < 4; ++nt) {
      const int kv = kvb + nt * 16 + lr;
#pragma unroll
      for (int r = 0; r < 4; ++r) {
        if (kv > qb + lg * 4 + r) s[nt][r] = -1e30f;
      }
    }
    float cm[4], al[4], rs[4];
#pragma unroll
    for (int r = 0; r < 4; ++r)
      cm[r] = fmaxf(fmaxf(s[0][r], s[1][r]), fmaxf(s[2][r], s[3][r]));
#pragma unroll
    for (int r = 0; r < 4; ++r) {
#pragma unroll
      for (int off = 1; off < 16; off <<= 1)
        cm[r] = fmaxf(cm[r], __shfl_xor(cm[r], off, 16));
    }
#pragma unroll
    for (int r = 0; r < 4; ++r) {
      const float mn = fmaxf(m_[r], cm[r]);
      al[r] = exp2f(m_[r] - mn);
      m_[r] = mn;
      rs[r] = 0.f;
    }
#pragma unroll
    for (int nt = 0; nt < 4; ++nt)
#pragma unroll
      for (int r = 0; r < 4; ++r) {
        const float p = exp2f(s[nt][r] - m_[r]);
        s[nt][r] = p;
        rs[r] += p;
      }
#pragma unroll
    for (int r = 0; r < 4; ++r) {
#pragma unroll
      for (int off = 1; off < 16; off <<= 1)
        rs[r] += __shfl_xor(rs[r], off, 16);
      l_[r] = l_[r] * al[r] + rs[r];
    }
#pragma unroll
    for (int dt = 0; dt < 8; ++dt) {
      f32x4 a = acc[dt];
      a[0] *= al[0]; a[1] *= al[1]; a[2] *= al[2]; a[3] *= al[3];
      acc[dt] = a;
    }

    // ---- P -> per-wave LDS (bf16), then PV -------------------------------
    short* pw = &Pb[wave][0];
#pragma unroll
    for (int nt = 0; nt < 4; ++nt)
#pragma unroll
      for (int r = 0; r < 4; ++r)
        pw[(lg * 4 + r) * 72 + nt * 16 + lr] = f2bf(s[nt][r]);
    asm volatile("s_waitcnt lgkmcnt(0)" ::: "memory");
    __builtin_amdgcn_sched_barrier(0);

#pragma unroll
    for (int ks = 0; ks < 2; ++ks) {
      s16x8 af = *(const s16x8*)(&Pb[wave][lr * 72 + ks * 32 + lg * 8]);
      s16x4 b0[8], b1[8];
#pragma unroll
      for (int dt = 0; dt < 8; ++dt) {
        // V B-frag: kv = ks*32 + lg*8 + j, d = dt*16 + lr via two tr_b16 reads
        const uint32_t addr =
            vb_base + (uint32_t)(((((ks * 8 + lg * 2) * 8 + dt) * 64) + lr * 4) * 2);
        asm volatile("ds_read_b64_tr_b16 %0, %2\n\t"
                     "ds_read_b64_tr_b16 %1, %2 offset:1024"
                     : "=&v"(b0[dt]), "=&v"(b1[dt])
                     : "v"(addr)
                     : "memory");
      }
      asm volatile("s_waitcnt lgkmcnt(0)" ::: "memory");
      __builtin_amdgcn_sched_barrier(0);
#pragma unroll
      for (int dt = 0; dt < 8; ++dt) {
        s16x8 bf = __builtin_shufflevector(b0[dt], b1[dt], 0, 1, 2, 3, 4, 5, 6, 7);
        acc[dt] = mfma16(af, bf, acc[dt]);
      }
    }
    __syncthreads();
  }

  // ---- epilogue: O = acc / l ---------------------------------------------
  float inv[4];
#pragma unroll
  for (int r = 0; r < 4; ++r) inv[r] = 1.0f / l_[r];
#pragma unroll
  for (int dt = 0; dt < 8; ++dt) {
#pragma unroll
    for (int r = 0; r < 4; ++r) {
      O[(size_t)(b * SEQ + qb + lg * 4 + r) * (NH * D) + hq * D + dt * 16 + lr] =
          acc[dt][r] * inv[r];
    }
  }
}

extern "C" void kernel_launch(void* const* d_in, const int* in_sizes, int n_in,
                              void* d_out, int out_size, void* d_ws, size_t ws_size,
                              hipStream_t stream) {
  const float* q = (const float*)d_in[0];
  const float* k = (const float*)d_in[1];
  const float* v = (const float*)d_in[2];
  float* o = (float*)d_out;
  dim3 grid(BATCH * NH * (SEQ / QTILE));  // 2048 blocks
  attn_fwd<<<grid, 256, 0, stream>>>(q, k, v, o);
}

// Round 7
// 279.030 us; speedup vs baseline: 2.0353x; 2.0353x over previous
//
#include <hip/hip_runtime.h>
#include <hip/hip_bf16.h>
#include <stdint.h>

// Varlen causal GQA prefill attention, MI355X (gfx950).
// B=4, S=2048, Hq=16, Hkv=4 (G=4), D=128, fp32 I/O, bf16 MFMA internally.
// Structure: 256 thr = 4 waves x 32 q-rows (QTILE=128), KV chunks of 64,
// double-buffered K/V in LDS, swapped QK^T (S^T via mfma(K,Q)), in-register
// softmax (permlane32_swap), P->PV frags via cvt_pk+permlane (no P LDS),
// PV as O^T = V^T * P^T with V read through ds_read_b64_tr_b16.
#define NH    16
#define HKVN  4
#define D     128
#define SEQ   2048
#define BATCH 4
#define QTILE 128
#define KVC   64

#define SCALE_LOG2E 0.12751741f   // (1/sqrt(128)) * log2(e), folded into Q
#define THR 11.0f                 // defer-max threshold (log2 units, ~e^7.6)

typedef __attribute__((ext_vector_type(4)))  float    f32x4;
typedef __attribute__((ext_vector_type(16))) float    f32x16;
typedef __attribute__((ext_vector_type(8)))  short    s16x8;
typedef __attribute__((ext_vector_type(4)))  short    s16x4;
typedef __attribute__((ext_vector_type(4)))  uint32_t u32x4;
typedef __attribute__((ext_vector_type(8)))  __bf16   bf16x8;

__device__ __forceinline__ uint32_t cvt_pk(float lo, float hi) {
  uint32_t r;
  asm("v_cvt_pk_bf16_f32 %0, %1, %2" : "=v"(r) : "v"(lo), "v"(hi));
  return r;
}
// permlane32_swap(a,b): upper 32 lanes of a <-> lower 32 lanes of b.
// ret0 = {a_low | b_low}, ret1 = {a_high | b_high} (lane-pair l <-> l+32).
__device__ __forceinline__ void pswap(uint32_t& a, uint32_t& b) {
  auto r = __builtin_amdgcn_permlane32_swap(a, b, false, false);
  a = r[0];
  b = r[1];
}
__device__ __forceinline__ float cross_max(float x) {
  uint32_t a = __builtin_bit_cast(uint32_t, x), b = a;
  pswap(a, b);  // between a and b, each lane now has own + partner value
  return fmaxf(__builtin_bit_cast(float, a), __builtin_bit_cast(float, b));
}
__device__ __forceinline__ float cross_sum(float x) {
  uint32_t a = __builtin_bit_cast(uint32_t, x), b = a;
  pswap(a, b);
  return __builtin_bit_cast(float, a) + __builtin_bit_cast(float, b);
}
__device__ __forceinline__ f32x16 mfma32(s16x8 a, s16x8 b, f32x16 c) {
  return __builtin_amdgcn_mfma_f32_32x32x16_bf16(
      __builtin_bit_cast(bf16x8, a), __builtin_bit_cast(bf16x8, b), c, 0, 0, 0);
}

__global__ __launch_bounds__(256, 2) void attn_fwd(
    const float* __restrict__ Q, const float* __restrict__ K,
    const float* __restrict__ V, float* __restrict__ O) {
  // K: row-major [64][128] bf16, XOR-swizzled (short idx ^= (row&7)*8):
  // A-frag b128 reads are conflict-free under this pattern.
  // V: subtiled [kv/4][d/16][4][16] bf16 for ds_read_b64_tr_b16.
  __shared__ __align__(16) short KT[2][KVC * D];
  __shared__ __align__(16) short VT[2][KVC * D];

  const int bid = blockIdx.x;
  const int grp = bid >> 8;        // dispatch-order work pairing:
  const int i   = bid & 255;       // per-CU qt sums equalized, heavy first
  const int s   = i & 3;
  int qt;
  switch (grp) { case 0: qt = 15 - s; break; case 1: qt = s; break;
                 case 2: qt = 11 - s; break; default: qt = 4 + s; }
  const int bh  = i >> 2;          // 0..63 = b*16 + hq
  const int b   = bh >> 4;
  const int hq  = bh & 15;
  const int hkv = hq >> 2;

  const int tid  = threadIdx.x;
  const int wq   = tid >> 6;       // wave 0..3
  const int lane = tid & 63;
  const int l31  = lane & 31;
  const int h2   = lane >> 5;      // half 0/1
  const int h16  = (lane >> 4) & 1;
  const int l15  = lane & 15;

  const int q0   = qt * QTILE;
  const int qg   = q0 + wq * 32 + l31;   // this lane's q row (global in seq)
  const int qmin = q0 + wq * 32;
  const int qmax = qmin + 31;
  const int nch  = 2 * qt + 2;

  // ---- Q as B-frags: qf[kb][j] = Q[qg][kb*16 + h2*8 + j] * SCALE ----------
  const float* qp = Q + (size_t)(b * SEQ + qg) * (NH * D) + hq * D;
  s16x8 qf[8];
#pragma unroll
  for (int kb = 0; kb < 8; ++kb) {
    f32x4 x0 = *(const f32x4*)(qp + kb * 16 + h2 * 8);
    f32x4 x1 = *(const f32x4*)(qp + kb * 16 + h2 * 8 + 4);
    u32x4 w;
    w[0] = cvt_pk(x0[0] * SCALE_LOG2E, x0[1] * SCALE_LOG2E);
    w[1] = cvt_pk(x0[2] * SCALE_LOG2E, x0[3] * SCALE_LOG2E);
    w[2] = cvt_pk(x1[0] * SCALE_LOG2E, x1[1] * SCALE_LOG2E);
    w[3] = cvt_pk(x1[2] * SCALE_LOG2E, x1[3] * SCALE_LOG2E);
    qf[kb] = __builtin_bit_cast(s16x8, w);
  }

  f32x16 acc[4];
#pragma unroll
  for (int dt = 0; dt < 4; ++dt)
#pragma unroll
    for (int r = 0; r < 16; ++r) acc[dt][r] = 0.f;
  float m_r = -1e30f, l_r = 0.f;

  const float* Kg = K + (size_t)b * SEQ * (HKVN * D) + hkv * D;
  const float* Vg = V + (size_t)b * SEQ * (HKVN * D) + hkv * D;

  const int srow = tid >> 2;        // staging: 4 threads per kv row
  const int scol = (tid & 3) * 32;  // 32 cols each

  f32x4 kl[8], vl[8];
#define STAGE_LOADS(kvb_) do {                                               \
    const float* kr_ = Kg + (size_t)((kvb_) + srow) * (HKVN * D) + scol;     \
    const float* vr_ = Vg + (size_t)((kvb_) + srow) * (HKVN * D) + scol;     \
    _Pragma("unroll") for (int u = 0; u < 8; ++u)                            \
      kl[u] = *(const f32x4*)(kr_ + u * 4);                                  \
    _Pragma("unroll") for (int u = 0; u < 8; ++u)                            \
      vl[u] = *(const f32x4*)(vr_ + u * 4);                                  \
  } while (0)

#define STAGE_WRITES(nbuf_) do {                                             \
    short* kd_ = &KT[nbuf_][srow * D];                                       \
    short* vd_ = &VT[nbuf_][0];                                              \
    _Pragma("unroll") for (int g = 0; g < 4; ++g) {                          \
      u32x4 wk_, wv_;                                                        \
      wk_[0] = cvt_pk(kl[2*g][0], kl[2*g][1]);                               \
      wk_[1] = cvt_pk(kl[2*g][2], kl[2*g][3]);                               \
      wk_[2] = cvt_pk(kl[2*g+1][0], kl[2*g+1][1]);                           \
      wk_[3] = cvt_pk(kl[2*g+1][2], kl[2*g+1][3]);                           \
      wv_[0] = cvt_pk(vl[2*g][0], vl[2*g][1]);                               \
      wv_[1] = cvt_pk(vl[2*g][2], vl[2*g][3]);                               \
      wv_[2] = cvt_pk(vl[2*g+1][0], vl[2*g+1][1]);                           \
      wv_[3] = cvt_pk(vl[2*g+1][2], vl[2*g+1][3]);                           \
      *(u32x4*)(kd_ + ((scol + g * 8) ^ ((srow & 7) * 8))) = wk_;            \
      const int d_ = scol + g * 8;                                           \
      *(u32x4*)(vd_ + ((srow >> 2) * 8 + (d_ >> 4)) * 64 +                   \
                (srow & 3) * 16 + (d_ & 15)) = wv_;                          \
    }                                                                        \
  } while (0)

  // ---- prologue: stage chunk 0 into buffer 0 ------------------------------
  STAGE_LOADS(0);
  STAGE_WRITES(0);
  __syncthreads();

  for (int c = 0; c < nch; ++c) {
    const int cur = c & 1, nxt = cur ^ 1;
    const int kvb = c * KVC;
    const bool have_next = (c + 1 < nch);
    const bool active = (kvb <= qmax);   // wave-uniform

    if (have_next) {
      STAGE_LOADS(kvb + KVC);            // issue early; used after softmax
      __builtin_amdgcn_sched_barrier(0);
    }

    f32x16 st[2];
    s16x8 pf[4];
    if (active) {
      // ---- S^T = K * Q  (2 kv-tiles x K=128) -----------------------------
#pragma unroll
      for (int t = 0; t < 2; ++t) {
#pragma unroll
        for (int r = 0; r < 16; ++r) st[t][r] = 0.f;
        const int row = t * 32 + l31;
        const short* rp = &KT[cur][row * D];
        const int sw = (row & 7) * 8;
#pragma unroll
        for (int kb = 0; kb < 8; ++kb) {
          s16x8 kf = *(const s16x8*)(rp + ((kb * 16 + h2 * 8) ^ sw));
          st[t] = mfma32(kf, qf[kb], st[t]);
        }
      }
      // ---- causal mask (diagonal chunk only) -----------------------------
      if (kvb + 63 > qmin) {
#pragma unroll
        for (int t = 0; t < 2; ++t)
#pragma unroll
          for (int r = 0; r < 16; ++r) {
            const int kv = kvb + t * 32 + (r & 3) + 8 * (r >> 2) + 4 * h2;
            if (kv > qg) st[t][r] = -1e30f;
          }
      }
      // ---- online softmax, fully lane-local (q = lane&31) ----------------
      float pm = st[0][0];
#pragma unroll
      for (int t = 0; t < 2; ++t)
#pragma unroll
        for (int r = 0; r < 16; ++r) pm = fmaxf(pm, st[t][r]);
      const float pmax = cross_max(pm);
      if (__any(pmax > m_r + THR)) {     // defer-max: skip tiny growth
        const float mn = fmaxf(m_r, pmax);
        const float al = __builtin_amdgcn_exp2f(m_r - mn);
        m_r = mn;
        l_r *= al;
#pragma unroll
        for (int dt = 0; dt < 4; ++dt)
#pragma unroll
          for (int r = 0; r < 16; ++r) acc[dt][r] *= al;
      }
      float p[32];
      float rs = 0.f;
#pragma unroll
      for (int t = 0; t < 2; ++t)
#pragma unroll
        for (int r = 0; r < 16; ++r) {
          const float e = __builtin_amdgcn_exp2f(st[t][r] - m_r);
          p[t * 16 + r] = e;
          rs += e;
        }
      l_r += cross_sum(rs);
      // ---- P -> PV B-frags via cvt_pk + permlane32_swap (T12) ------------
      // word0 needs {h2=0: own (p[o],p[o+1]); h2=1: partner (p[o+4],p[o+5])}
      // = ret0 of pswap(low-word, high-word); word2 = ret1. (Guide m214v22.)
#pragma unroll
      for (int ks = 0; ks < 4; ++ks) {
        const int o = (ks >> 1) * 16 + (ks & 1) * 8;
        uint32_t A0 = cvt_pk(p[o + 0], p[o + 1]);
        uint32_t A1 = cvt_pk(p[o + 2], p[o + 3]);
        uint32_t B0 = cvt_pk(p[o + 4], p[o + 5]);
        uint32_t B1 = cvt_pk(p[o + 6], p[o + 7]);
        pswap(A0, B0);  // A0 -> word j01, B0 -> word j45
        pswap(A1, B1);  // A1 -> word j23, B1 -> word j67
        u32x4 w; w[0] = A0; w[1] = A1; w[2] = B0; w[3] = B1;
        pf[ks] = __builtin_bit_cast(s16x8, w);
      }
    }

    if (have_next) {
      STAGE_WRITES(nxt);  // compiler inserts vmcnt before first use of kl/vl
    }

    if (active) {
      // ---- O^T += V^T * P^T  (V as A via tr_b16 reads) -------------------
      const uint32_t vbase = (uint32_t)(uintptr_t)&VT[cur][0];
#pragma unroll
      for (int dt = 0; dt < 4; ++dt) {
        s16x4 a0[4], a1[4];
#pragma unroll
        for (int ks = 0; ks < 4; ++ks) {
          const uint32_t ad =
              vbase + (uint32_t)((((ks * 4 + h2 * 2) * 8 + 2 * dt + h16) * 64 +
                                  l15 * 4) * 2);
          asm volatile("ds_read_b64_tr_b16 %0, %2\n\t"
                       "ds_read_b64_tr_b16 %1, %2 offset:1024"
                       : "=&v"(a0[ks]), "=&v"(a1[ks])
                       : "v"(ad)
                       : "memory");
        }
        asm volatile("s_waitcnt lgkmcnt(0)" ::: "memory");
        __builtin_amdgcn_sched_barrier(0);
#pragma unroll
        for (int ks = 0; ks < 4; ++ks) {
          s16x8 vf = __builtin_shufflevector(a0[ks], a1[ks], 0, 1, 2, 3, 4, 5, 6, 7);
          acc[dt] = mfma32(vf, pf[ks], acc[dt]);
        }
      }
    }
    __syncthreads();
  }

  // ---- epilogue: O = acc^T / l  (acc col q = lane&31) ----------------------
  const float inv = 1.0f / l_r;
  float* op = O + (size_t)(b * SEQ + qg) * (NH * D) + hq * D;
#pragma unroll
  for (int dt = 0; dt < 4; ++dt) {
#pragma unroll
    for (int rg = 0; rg < 4; ++rg) {
      f32x4 o;
      o[0] = acc[dt][rg * 4 + 0] * inv;
      o[1] = acc[dt][rg * 4 + 1] * inv;
      o[2] = acc[dt][rg * 4 + 2] * inv;
      o[3] = acc[dt][rg * 4 + 3] * inv;
      *(f32x4*)(op + dt * 32 + rg * 8 + h2 * 4) = o;
    }
  }
}

extern "C" void kernel_launch(void* const* d_in, const int* in_sizes, int n_in,
                              void* d_out, int out_size, void* d_ws, size_t ws_size,
                              hipStream_t stream) {
  const float* q = (const float*)d_in[0];
  const float* k = (const float*)d_in[1];
  const float* v = (const float*)d_in[2];
  float* o = (float*)d_out;
  dim3 grid(BATCH * NH * (SEQ / QTILE));  // 1024 blocks
  attn_fwd<<<grid, 256, 0, stream>>>(q, k, v, o);
}